// Round 9
// baseline (510.921 us; speedup 1.0000x reference)
//
#include <hip/hip_runtime.h>
#include <hip/hip_fp16.h>

typedef _Float16 half8 __attribute__((ext_vector_type(8)));
typedef float floatx4 __attribute__((ext_vector_type(4)));

#define TAU 0.25f
#define CMAX 128

// Barrier WITHOUT the vmcnt(0) drain __syncthreads() would emit: only ds-ops
// must be complete/visible (LDS is CU-local).  In-flight global prefetch
// loads (thread-private VGPR dests) stay in flight across the barrier.
#define BARRIER_LG() asm volatile("s_waitcnt lgkmcnt(0)\n\ts_barrier" ::: "memory")

__device__ inline unsigned long long score_key(float sc, int k) {
  unsigned uu = __float_as_uint(sc);
  uu ^= (unsigned)(((int)uu >> 31)) | 0x80000000u;  // monotone float->u32
  return ((unsigned long long)uu << 32) | (unsigned)k;
}

// ---------------------------------------------------------------------------
// Layouts:
//   xh : [kgran=0..63][row=0..32767] of half8  (granule-major, R6: 2x gemm)
//   cth: [kgran=0..63][n  =0.. 8191] of half8
//   xt : [row][c=0..511] fp32   (R9: coalesced refine x-reads; optional)
//   ct : [n  ][c=0..511] fp32   (R9: coalesced refine cen-reads; optional)
// R9 rationale: cand_refine/fullscan were the last strided patterns —
// xs loads stride 8KB (512 txn/row) and candidate dots read cen columns
// stride 32KB (512 txn/candidate).  xt/ct make both contiguous.  Values are
// bit-identical fp32 copies consumed in the identical fmaf order -> labels
// unchanged.  If ws too small for the +80MB, null pointers select the old
// strided path (no correctness risk).
// ---------------------------------------------------------------------------

// Kernel 0a: transpose x [b=16, c=512, s=2048] f32 -> xh granule-major (+ xt)
__global__ void tsplit_x(const float* __restrict__ x, _Float16* __restrict__ xh,
                         float* __restrict__ xt) {
  __shared__ float tile[32][65];  // [c][s], pad -> 2-way bank max
  const int s0 = blockIdx.x * 64;
  const int c0 = blockIdx.y * 32;
  const int b = blockIdx.z;
  const int tx = threadIdx.x, ty = threadIdx.y;
  const float* src = x + ((size_t)b * 512 + c0) * 2048 + s0;
#pragma unroll
  for (int i = ty; i < 32; i += 8) {
    tile[i][tx] = src[(size_t)i * 2048 + tx];
    tile[i][tx + 32] = src[(size_t)i * 2048 + tx + 32];
  }
  __syncthreads();
  const int t = ty * 32 + tx;
  {
    const int g = t >> 6;   // granule-in-block 0..3
    const int j = t & 63;   // s-offset 0..63
    half8 pk;
#pragma unroll
    for (int i = 0; i < 8; ++i) pk[i] = (_Float16)tile[g * 8 + i][j];
    const int row = b * 2048 + s0 + j;
    ((half8*)xh)[(size_t)(c0 / 8 + g) * 32768 + row] = pk;
  }
  if (xt) {
    const int jq = t >> 2, q = t & 3;  // jq: s-offset, q: c-octet
    const int row = b * 2048 + s0 + jq;
    floatx4 w0, w1;
#pragma unroll
    for (int i = 0; i < 4; ++i) w0[i] = tile[q * 8 + i][jq];
#pragma unroll
    for (int i = 0; i < 4; ++i) w1[i] = tile[q * 8 + 4 + i][jq];
    floatx4* dst = (floatx4*)(xt + (size_t)row * 512 + c0 + q * 8);
    dst[0] = w0;
    dst[1] = w1;
  }
}

// Kernel 0b: transpose centroids [c=512, n=8192] f32 -> cth granule-major (+ ct)
__global__ void tsplit_c(const float* __restrict__ c, _Float16* __restrict__ cth,
                         float* __restrict__ ct) {
  __shared__ float tile[32][65];  // [c][n]
  const int n0 = blockIdx.x * 64;
  const int c0 = blockIdx.y * 32;
  const int tx = threadIdx.x, ty = threadIdx.y;
#pragma unroll
  for (int i = ty; i < 32; i += 8) {
    tile[i][tx] = c[(size_t)(c0 + i) * 8192 + n0 + tx];
    tile[i][tx + 32] = c[(size_t)(c0 + i) * 8192 + n0 + tx + 32];
  }
  __syncthreads();
  const int t = ty * 32 + tx;
  {
    const int g = t >> 6;   // granule-in-block 0..3
    const int j = t & 63;   // n-offset 0..63
    half8 pk;
#pragma unroll
    for (int i = 0; i < 8; ++i) pk[i] = (_Float16)tile[g * 8 + i][j];
    ((half8*)cth)[(size_t)(c0 / 8 + g) * 8192 + n0 + j] = pk;
  }
  if (ct) {
    const int jq = t >> 2, q = t & 3;
    floatx4 w0, w1;
#pragma unroll
    for (int i = 0; i < 4; ++i) w0[i] = tile[q * 8 + i][jq];
#pragma unroll
    for (int i = 0; i < 4; ++i) w1[i] = tile[q * 8 + 4 + i][jq];
    floatx4* dst = (floatx4*)(ct + (size_t)(n0 + jq) * 512 + c0 + q * 8);
    dst[0] = w0;
    dst[1] = w1;
  }
}

// ---------------------------------------------------------------------------
// Kernel 0c: c_sq[n] = sum_c C[c][n]^2 (fp32, exact inputs) + zero counters.
// ---------------------------------------------------------------------------
__global__ void csq_kernel(const float* __restrict__ c, float* __restrict__ csq,
                           unsigned int* __restrict__ cnts) {
  __shared__ float red[256];
  const int t = threadIdx.x;
  if (blockIdx.x == 0 && t < 2) cnts[t] = 0u;
  const int nl = t & 63;
  const int cs = t >> 6;  // 0..3
  const int n = blockIdx.x * 64 + nl;
  float acc = 0.f;
  for (int cc = cs; cc < 512; cc += 4) {
    float v = c[(size_t)cc * 8192 + n];
    acc = fmaf(v, v, acc);
  }
  red[t] = acc;
  __syncthreads();
  if (t < 64) csq[n] = red[t] + red[t + 64] + red[t + 128] + red[t + 192];
}

// ---------------------------------------------------------------------------
// Kernel 1: f16 GEMM + per-(row, nblock) top-2.  (R6 structure, measured
//   308 us / MfmaUtil 43.6 / ~893 TF — at the documented plain-HIP 2-phase
//   128^2 ceiling.  UNCHANGED this round.)
// ---------------------------------------------------------------------------
__launch_bounds__(256, 4)
__global__ void gemm_top2(const _Float16* __restrict__ xh, const _Float16* __restrict__ cth,
                          const float* __restrict__ csq, float* __restrict__ pv1,
                          int* __restrict__ pi1, float* __restrict__ pv2) {
  __shared__ __align__(16) unsigned char smem[32768];  // 2 bufs x (A 8K + B 8K)
  __shared__ float ep_v1[128][2], ep_v2[128][2];
  __shared__ int ep_i1[128][2];

  const int t = threadIdx.x;
  const int m0 = blockIdx.x * 128;
  const int n0 = blockIdx.y * 128;

  // staging: thread t owns rows m0+(t&127) / n0+(t&127), kq parity t>>7.
  const int srow = t & 127;
  const int kqp = t >> 7;  // 0/1 ; kq = kqp + 2*c2
  const half8* Ag = (const half8*)xh + (size_t)(m0 + srow);   // + kg*32768
  const half8* Bg = (const half8*)cth + (size_t)(n0 + srow);  // + kg*8192

  const int l = t & 63;
  const int w = t >> 6;
  const int wm = w >> 1, wn = w & 1;
  const int l15 = l & 15, lq = l >> 4;
  const int aBase = lq * 128 + wm * 64 + l15;        // + mf*16  (half8 idx)
  const int bBase = 512 + lq * 128 + wn * 64 + l15;  // + nf*16

  floatx4 acc[4][4] = {};
  const half8* S = (const half8*)smem;
  half8* SW = (half8*)smem;

  half8 pfA0, pfA1, pfB0, pfB1;
  // prologue: load kc=0 (granules kqp, kqp+2), write buf0, load kc=1
  pfA0 = Ag[(size_t)(kqp)*32768];
  pfA1 = Ag[(size_t)(kqp + 2) * 32768];
  pfB0 = Bg[(size_t)(kqp)*8192];
  pfB1 = Bg[(size_t)(kqp + 2) * 8192];
  SW[t] = pfA0; SW[256 + t] = pfA1;
  SW[512 + t] = pfB0; SW[768 + t] = pfB1;
  pfA0 = Ag[(size_t)(4 + kqp) * 32768];
  pfA1 = Ag[(size_t)(4 + kqp + 2) * 32768];
  pfB0 = Bg[(size_t)(4 + kqp) * 8192];
  pfB1 = Bg[(size_t)(4 + kqp + 2) * 8192];

  for (int kc = 0; kc < 16; ++kc) {
    BARRIER_LG();  // ds ordered; global prefetch stays in flight
    const int bo = (kc & 1) * 1024;
    half8 a[4], b[4];
#pragma unroll
    for (int f = 0; f < 4; ++f) {
      a[f] = S[bo + aBase + f * 16];
      b[f] = S[bo + bBase + f * 16];
    }
#pragma unroll
    for (int mf = 0; mf < 4; ++mf)
#pragma unroll
      for (int nf = 0; nf < 4; ++nf)
        acc[mf][nf] = __builtin_amdgcn_mfma_f32_16x16x32_f16(b[nf], a[mf], acc[mf][nf], 0, 0, 0);
    if (kc < 15) {
      const int wo = ((kc + 1) & 1) * 1024;
      SW[wo + t] = pfA0; SW[wo + 256 + t] = pfA1;
      SW[wo + 512 + t] = pfB0; SW[wo + 768 + t] = pfB1;
      if (kc < 14) {
        const int o = (kc + 2) * 4;
        pfA0 = Ag[(size_t)(o + kqp) * 32768];
        pfA1 = Ag[(size_t)(o + kqp + 2) * 32768];
        pfB0 = Bg[(size_t)(o + kqp) * 8192];
        pfB1 = Bg[(size_t)(o + kqp + 2) * 8192];
      }
    }
  }

  // ---- epilogue: top-2, lane-local over 16 centroids then 2 merge rounds.
  // acc[mf][nf][reg] = dot(xrow = m0+wm*64+mf*16+l15,
  //                        cent = n0+wn*64+nf*16+lq*4+reg)
  floatx4 cs4[4];
  const floatx4* csq4 = (const floatx4*)csq;
#pragma unroll
  for (int nf = 0; nf < 4; ++nf)
    cs4[nf] = csq4[(n0 >> 2) + wn * 16 + nf * 4 + lq];

  const int siBase = n0 + wn * 64 + lq * 4;

#pragma unroll
  for (int mf = 0; mf < 4; ++mf) {
    float v1 = INFINITY, v2 = INFINITY;
    int i1 = 0;
#pragma unroll
    for (int nf = 0; nf < 4; ++nf) {
#pragma unroll
      for (int reg = 0; reg < 4; ++reg) {
        float sv = fmaf(-2.f, acc[mf][nf][reg], cs4[nf][reg]);
        int si = siBase + nf * 16 + reg;
        if (sv < v1) { v2 = v1; v1 = sv; i1 = si; }
        else if (sv < v2) { v2 = sv; }
      }
    }
    // merge across the 4 lq-groups (lanes l15, l15+16, l15+32, l15+48)
#pragma unroll
    for (int off = 16; off <= 32; off <<= 1) {
      float w1 = __shfl_xor(v1, off, 64);
      int j1 = __shfl_xor(i1, off, 64);
      float w2 = __shfl_xor(v2, off, 64);
      if (w1 < v1 || (w1 == v1 && j1 < i1)) {
        v2 = fminf(v1, w2);
        v1 = w1; i1 = j1;
      } else {
        v2 = fminf(v2, w1);
      }
    }
    if (lq == 0) {
      int rl = wm * 64 + mf * 16 + l15;
      ep_v1[rl][wn] = v1;
      ep_i1[rl][wn] = i1;
      ep_v2[rl][wn] = v2;
    }
  }
  __syncthreads();
  if (t < 128) {
    float v1 = ep_v1[t][0], v2 = ep_v2[t][0];
    int i1 = ep_i1[t][0];
    float w1 = ep_v1[t][1], w2 = ep_v2[t][1];
    int j1 = ep_i1[t][1];
    if (w1 < v1 || (w1 == v1 && j1 < i1)) {
      v2 = fminf(v1, w2);
      v1 = w1; i1 = j1;
    } else {
      v2 = fminf(v2, w1);
    }
    const size_t o = (size_t)blockIdx.y * 32768 + m0 + t;
    pv1[o] = v1;
    pi1[o] = i1;
    pv2[o] = v2;
  }
}

// ---------------------------------------------------------------------------
// Kernel 2 (R7): merge 64 nblock top-2s — parallel over nb.  Associative
//   merge over total order (value, index) -> bit-identical to sequential.
// ---------------------------------------------------------------------------
__global__ void final_top2(const float* __restrict__ pv1, const int* __restrict__ pi1,
                           const float* __restrict__ pv2, int* __restrict__ out,
                           float* __restrict__ rowbest, unsigned int* __restrict__ cnt,
                           int* __restrict__ list) {
  __shared__ float sv1[8][33], sv2[8][33];
  __shared__ int si1[8][33];
  const int t = threadIdx.x;
  const int r = t & 31, c = t >> 5;  // c = nb-chunk 0..7
  const int row = blockIdx.x * 32 + r;
  float v1 = INFINITY, v2 = INFINITY;
  int i1 = 0;
#pragma unroll
  for (int k = 0; k < 8; ++k) {
    const size_t o = (size_t)(c * 8 + k) * 32768 + row;
    float w1 = pv1[o], w2 = pv2[o];
    int j1 = pi1[o];
    if (w1 < v1 || (w1 == v1 && j1 < i1)) {
      v2 = fminf(v1, w2);
      v1 = w1; i1 = j1;
    } else {
      v2 = fminf(v2, w1);
    }
  }
  sv1[c][r] = v1;
  sv2[c][r] = v2;
  si1[c][r] = i1;
  __syncthreads();
  if (c == 0) {
#pragma unroll
    for (int k = 1; k < 8; ++k) {
      float w1 = sv1[k][r], w2 = sv2[k][r];
      int j1 = si1[k][r];
      if (w1 < v1 || (w1 == v1 && j1 < i1)) {
        v2 = fminf(v1, w2);
        v1 = w1; i1 = j1;
      } else {
        v2 = fminf(v2, w1);
      }
    }
    out[row] = i1;
    rowbest[row] = v1;
    if (v2 - v1 < TAU) {
      unsigned int pos = atomicAdd(cnt, 1u);
      list[pos] = row;
    }
  }
}

// ---------------------------------------------------------------------------
// Kernel 3: candidate-set exact rescore for flagged rows.
//   R9: xs load from xt (coalesced contiguous) and candidate dot from ct
//   (contiguous per candidate) when available; identical fp32 values in
//   identical fmaf order -> bit-identical results.
// ---------------------------------------------------------------------------
__global__ void cand_refine(const float* __restrict__ x, const float* __restrict__ cen,
                            const float* __restrict__ xt, const float* __restrict__ ct,
                            const float* __restrict__ csq, const float* __restrict__ pv1,
                            const int* __restrict__ pi1, const float* __restrict__ pv2,
                            const float* __restrict__ rowbest,
                            const unsigned int* __restrict__ cnt, const int* __restrict__ list,
                            unsigned int* __restrict__ cnt2, int* __restrict__ list2,
                            unsigned long long* __restrict__ slots, int* __restrict__ out) {
  __shared__ float xs[512];
  __shared__ int cand[CMAX];
  __shared__ int ccnt_s, needfull_s;
  __shared__ unsigned long long wbest[4];
  const int t = threadIdx.x;
  const int lane = t & 63, wid = t >> 6;
  const int n = (int)*cnt;
  for (int u = blockIdx.x; u < n; u += gridDim.x) {
    __syncthreads();  // protect previous iteration's xs/cand readers
    const int row = list[u];
    const int b = row >> 11, s = row & 2047;
    if (t == 0) { ccnt_s = 0; needfull_s = 0; }
    __syncthreads();
    if (xt) {
      xs[t] = xt[(size_t)row * 512 + t];
      xs[t + 256] = xt[(size_t)row * 512 + t + 256];
    } else {
      xs[t] = x[((size_t)(b * 512 + t)) * 2048 + s];
      xs[t + 256] = x[((size_t)(b * 512 + t + 256)) * 2048 + s];
    }
    const float thr = rowbest[row] + TAU;
    if (t < 64) {
      const size_t o = (size_t)t * 32768 + row;
      float w1 = pv1[o];
      if (w1 < thr) {
        int p = atomicAdd(&ccnt_s, 1);
        if (p < CMAX) cand[p] = pi1[o];
        if (pv2[o] < thr) needfull_s = 1;
      }
    }
    __syncthreads();
    int ccnt = ccnt_s < CMAX ? ccnt_s : CMAX;
    unsigned long long best = ~0ULL;
    if (ct) {
      for (int ci = wid; ci < ccnt; ci += 4) {
        const int k = cand[ci];
        const float* ck = ct + (size_t)k * 512;
        float p0 = 0.f, p1 = 0.f;
#pragma unroll
        for (int j = 0; j < 4; ++j)
          p0 = fmaf(xs[lane + 64 * j], ck[lane + 64 * j], p0);
#pragma unroll
        for (int j = 4; j < 8; ++j)
          p1 = fmaf(xs[lane + 64 * j], ck[lane + 64 * j], p1);
        float d = p0 + p1;
#pragma unroll
        for (int off = 32; off >= 1; off >>= 1) d += __shfl_xor(d, off, 64);
        unsigned long long key = score_key(fmaf(-2.f, d, csq[k]), k);
        if (key < best) best = key;
      }
    } else {
      for (int ci = wid; ci < ccnt; ci += 4) {
        const int k = cand[ci];
        float p0 = 0.f, p1 = 0.f;
#pragma unroll
        for (int j = 0; j < 4; ++j)
          p0 = fmaf(xs[lane + 64 * j], cen[(size_t)(lane + 64 * j) * 8192 + k], p0);
#pragma unroll
        for (int j = 4; j < 8; ++j)
          p1 = fmaf(xs[lane + 64 * j], cen[(size_t)(lane + 64 * j) * 8192 + k], p1);
        float d = p0 + p1;
#pragma unroll
        for (int off = 32; off >= 1; off >>= 1) d += __shfl_xor(d, off, 64);
        unsigned long long key = score_key(fmaf(-2.f, d, csq[k]), k);
        if (key < best) best = key;
      }
    }
    if (lane == 0) wbest[wid] = best;
    __syncthreads();
    if (t == 0) {
      unsigned long long m = wbest[0];
#pragma unroll
      for (int w2 = 1; w2 < 4; ++w2)
        if (wbest[w2] < m) m = wbest[w2];
      out[row] = (int)(unsigned)(m & 0xFFFFFFFFULL);
      if (needfull_s) {
        slots[row] = ~0ULL;
        unsigned int pos = atomicAdd(cnt2, 1u);
        list2[pos] = row;
      }
    }
  }
}

// ---------------------------------------------------------------------------
// Kernel 4: full 8192-scan for the rare rows needing it.  (R9: xs from xt.)
// ---------------------------------------------------------------------------
__global__ void fullscan(const float* __restrict__ x, const float* __restrict__ cen,
                         const float* __restrict__ xt,
                         const float* __restrict__ csq, const unsigned int* __restrict__ cnt2,
                         const int* __restrict__ list2, unsigned long long* __restrict__ slots) {
  __shared__ float xs[512];
  __shared__ unsigned long long red[256];
  const int t = threadIdx.x;
  const int n2 = (int)*cnt2;
  const int units = n2 * 16;
  for (int u = blockIdx.x; u < units; u += gridDim.x) {
    __syncthreads();
    const int row = list2[u >> 4];
    const int sl = u & 15;
    const int b = row >> 11, s = row & 2047;
    if (xt) {
      xs[t] = xt[(size_t)row * 512 + t];
      xs[t + 256] = xt[(size_t)row * 512 + t + 256];
    } else {
      xs[t] = x[((size_t)(b * 512 + t)) * 2048 + s];
      xs[t + 256] = x[((size_t)(b * 512 + t + 256)) * 2048 + s];
    }
    __syncthreads();
    const int k0 = sl * 512 + t;
    float tot0 = 0.f, tot1 = 0.f;
#pragma unroll
    for (int ch = 0; ch < 4; ++ch) {
      float a0 = 0.f, a1 = 0.f;
      for (int c = ch * 128; c < ch * 128 + 128; ++c) {
        float xv = xs[c];
        a0 = fmaf(xv, cen[(size_t)c * 8192 + k0], a0);
        a1 = fmaf(xv, cen[(size_t)c * 8192 + k0 + 256], a1);
      }
      tot0 += a0;
      tot1 += a1;
    }
    unsigned long long k1 = score_key(fmaf(-2.f, tot0, csq[k0]), k0);
    unsigned long long k2 = score_key(fmaf(-2.f, tot1, csq[k0 + 256]), k0 + 256);
    red[t] = k1 < k2 ? k1 : k2;
    __syncthreads();
    for (int off = 128; off >= 1; off >>= 1) {
      if (t < off && red[t + off] < red[t]) red[t] = red[t + off];
      __syncthreads();
    }
    if (t == 0) atomicMin(&slots[row], red[0]);
  }
}

// ---------------------------------------------------------------------------
// Kernel 5: fold fullscan results into labels.
// ---------------------------------------------------------------------------
__global__ void fixup2(const unsigned int* __restrict__ cnt2, const int* __restrict__ list2,
                       const unsigned long long* __restrict__ slots, int* __restrict__ out) {
  const int n2 = (int)*cnt2;
  for (int i = blockIdx.x * blockDim.x + threadIdx.x; i < n2; i += blockDim.x * gridDim.x) {
    const int row = list2[i];
    out[row] = (int)(unsigned)(slots[row] & 0xFFFFFFFFULL);
  }
}

// ---------------------------------------------------------------------------
// Fallback (only if ws too small): exact distances, slow but correct.
// ---------------------------------------------------------------------------
__global__ void fallback_kernel(const float* __restrict__ x, const float* __restrict__ cen,
                                int* __restrict__ out) {
  __shared__ float xrow[512];
  __shared__ float rv[256];
  __shared__ int ri[256];
  const int row = blockIdx.x;
  const int b = row >> 11, s = row & 2047;
  const int t = threadIdx.x;
  for (int c = t; c < 512; c += 256) xrow[c] = x[((size_t)b * 512 + c) * 2048 + s];
  __syncthreads();
  float bv = INFINITY;
  int bi = 0;
  for (int k = t; k < 8192; k += 256) {
    float d = 0.f;
    for (int c = 0; c < 512; ++c) {
      float diff = xrow[c] - cen[(size_t)c * 8192 + k];
      d = fmaf(diff, diff, d);
    }
    if (d < bv) { bv = d; bi = k; }
  }
  rv[t] = bv;
  ri[t] = bi;
  __syncthreads();
  for (int off = 128; off > 0; off >>= 1) {
    if (t < off) {
      if (rv[t + off] < rv[t] || (rv[t + off] == rv[t] && ri[t + off] < ri[t])) {
        rv[t] = rv[t + off];
        ri[t] = ri[t + off];
      }
    }
    __syncthreads();
  }
  if (t == 0) out[row] = ri[0];
}

// ---------------------------------------------------------------------------
extern "C" void kernel_launch(void* const* d_in, const int* in_sizes, int n_in,
                              void* d_out, int out_size, void* d_ws, size_t ws_size,
                              hipStream_t stream) {
  const float* x = (const float*)d_in[0];    // [16, 512, 2048]
  const float* cen = (const float*)d_in[1];  // [512, 8192]
  int* out = (int*)d_out;                    // [32768] int32 labels

  const size_t XSZ = (size_t)32768 * 512;  // halfs
  const size_t CSZ = (size_t)8192 * 512;   // halfs
  const size_t OFF_CTH = XSZ * 2;
  const size_t OFF_CSQ = OFF_CTH + CSZ * 2;
  const size_t OFF_PV1 = OFF_CSQ + 8192 * 4;
  const size_t OFF_PI1 = OFF_PV1 + (size_t)64 * 32768 * 4;
  const size_t OFF_PV2 = OFF_PI1 + (size_t)64 * 32768 * 4;
  const size_t OFF_RB = OFF_PV2 + (size_t)64 * 32768 * 4;
  const size_t OFF_SLOT = OFF_RB + (size_t)32768 * 4;
  const size_t OFF_LIST = OFF_SLOT + (size_t)32768 * 8;
  const size_t OFF_LIST2 = OFF_LIST + (size_t)32768 * 4;
  const size_t OFF_CNT = OFF_LIST2 + (size_t)32768 * 4;
  const size_t NEED = OFF_CNT + 16;
  // optional fp32 transposed copies for the refine path (R9)
  const size_t OFF_XT = (NEED + 255) & ~(size_t)255;
  const size_t OFF_CT = OFF_XT + (size_t)32768 * 512 * 4;
  const size_t NEED_FULL = OFF_CT + (size_t)8192 * 512 * 4;

  if (ws_size < NEED) {
    fallback_kernel<<<32768, 256, 0, stream>>>(x, cen, out);
    return;
  }

  char* ws = (char*)d_ws;
  _Float16* xh = (_Float16*)ws;
  _Float16* cth = (_Float16*)(ws + OFF_CTH);
  float* csq = (float*)(ws + OFF_CSQ);
  float* pv1 = (float*)(ws + OFF_PV1);
  int* pi1 = (int*)(ws + OFF_PI1);
  float* pv2 = (float*)(ws + OFF_PV2);
  float* rowbest = (float*)(ws + OFF_RB);
  unsigned long long* slots = (unsigned long long*)(ws + OFF_SLOT);
  int* list = (int*)(ws + OFF_LIST);
  int* list2 = (int*)(ws + OFF_LIST2);
  unsigned int* cnts = (unsigned int*)(ws + OFF_CNT);  // [0]=cnt, [1]=cnt2
  const bool full = ws_size >= NEED_FULL;
  float* xt = full ? (float*)(ws + OFF_XT) : nullptr;
  float* ct = full ? (float*)(ws + OFF_CT) : nullptr;

  tsplit_x<<<dim3(32, 16, 16), dim3(32, 8), 0, stream>>>(x, xh, xt);
  tsplit_c<<<dim3(128, 16), dim3(32, 8), 0, stream>>>(cen, cth, ct);
  csq_kernel<<<128, 256, 0, stream>>>(cen, csq, cnts);
  gemm_top2<<<dim3(256, 64), 256, 0, stream>>>(xh, cth, csq, pv1, pi1, pv2);
  final_top2<<<1024, 256, 0, stream>>>(pv1, pi1, pv2, out, rowbest, cnts, list);
  cand_refine<<<512, 256, 0, stream>>>(x, cen, xt, ct, csq, pv1, pi1, pv2, rowbest,
                                       cnts, list, cnts + 1, list2, slots, out);
  fullscan<<<256, 256, 0, stream>>>(x, cen, xt, csq, cnts + 1, list2, slots);
  fixup2<<<4, 256, 0, stream>>>(cnts + 1, list2, slots, out);
}

// Round 11
// 479.769 us; speedup vs baseline: 1.0649x; 1.0649x over previous
//
#include <hip/hip_runtime.h>
#include <hip/hip_fp16.h>

typedef _Float16 half8 __attribute__((ext_vector_type(8)));
typedef float floatx4 __attribute__((ext_vector_type(4)));

#define TAU 0.25f
#define CMAX 128

__device__ inline unsigned long long score_key(float sc, int k) {
  unsigned uu = __float_as_uint(sc);
  uu ^= (unsigned)(((int)uu >> 31)) | 0x80000000u;  // monotone float->u32
  return ((unsigned long long)uu << 32) | (unsigned)k;
}

// ---------------------------------------------------------------------------
// Layouts: xh and cth are K-GRANULE-MAJOR (R6, measured 2x on gemm):
//   xh : [kgran=0..63][row=0..32767] of half8   (granule = 16B = 8 halfs of K)
//   cth: [kgran=0..63][n  =0.. 8191] of half8
// ---------------------------------------------------------------------------

// Kernel 0a: transpose x [b=16, c=512, s=2048] f32 -> xh k-granule-major f16
__global__ void tsplit_x(const float* __restrict__ x, _Float16* __restrict__ xh) {
  __shared__ float tile[32][65];  // [c][s], pad -> 2-way bank max
  const int s0 = blockIdx.x * 64;
  const int c0 = blockIdx.y * 32;
  const int b = blockIdx.z;
  const int tx = threadIdx.x, ty = threadIdx.y;
  const float* src = x + ((size_t)b * 512 + c0) * 2048 + s0;
#pragma unroll
  for (int i = ty; i < 32; i += 8) {
    tile[i][tx] = src[(size_t)i * 2048 + tx];
    tile[i][tx + 32] = src[(size_t)i * 2048 + tx + 32];
  }
  __syncthreads();
  const int t = ty * 32 + tx;
  const int g = t >> 6;   // granule-in-block 0..3
  const int j = t & 63;   // s-offset 0..63
  half8 pk;
#pragma unroll
  for (int i = 0; i < 8; ++i) pk[i] = (_Float16)tile[g * 8 + i][j];
  const int row = b * 2048 + s0 + j;
  ((half8*)xh)[(size_t)(c0 / 8 + g) * 32768 + row] = pk;
}

// Kernel 0b: transpose centroids [c=512, n=8192] f32 -> cth k-granule-major f16
__global__ void tsplit_c(const float* __restrict__ c, _Float16* __restrict__ cth) {
  __shared__ float tile[32][65];  // [c][n]
  const int n0 = blockIdx.x * 64;
  const int c0 = blockIdx.y * 32;
  const int tx = threadIdx.x, ty = threadIdx.y;
#pragma unroll
  for (int i = ty; i < 32; i += 8) {
    tile[i][tx] = c[(size_t)(c0 + i) * 8192 + n0 + tx];
    tile[i][tx + 32] = c[(size_t)(c0 + i) * 8192 + n0 + tx + 32];
  }
  __syncthreads();
  const int t = ty * 32 + tx;
  const int g = t >> 6;   // granule-in-block 0..3
  const int j = t & 63;   // n-offset 0..63
  half8 pk;
#pragma unroll
  for (int i = 0; i < 8; ++i) pk[i] = (_Float16)tile[g * 8 + i][j];
  ((half8*)cth)[(size_t)(c0 / 8 + g) * 8192 + n0 + j] = pk;
}

// ---------------------------------------------------------------------------
// Kernel 0c: c_sq[n] = sum_c C[c][n]^2 (fp32, exact inputs) + zero counters.
// ---------------------------------------------------------------------------
__global__ void csq_kernel(const float* __restrict__ c, float* __restrict__ csq,
                           unsigned int* __restrict__ cnts) {
  __shared__ float red[256];
  const int t = threadIdx.x;
  if (blockIdx.x == 0 && t < 2) cnts[t] = 0u;
  const int nl = t & 63;
  const int cs = t >> 6;  // 0..3
  const int n = blockIdx.x * 64 + nl;
  float acc = 0.f;
  for (int cc = cs; cc < 512; cc += 4) {
    float v = c[(size_t)cc * 8192 + n];
    acc = fmaf(v, v, acc);
  }
  red[t] = acc;
  __syncthreads();
  if (t < 64) csq[n] = red[t] + red[t + 64] + red[t + 128] + red[t + 192];
}

// ---------------------------------------------------------------------------
// Kernel 1: f16 GEMM + per-(row, nblock) top-2.
//   R11 = R10's LDS-port relief (global_load_lds staging: ds_writes gone,
//   -33% LDS-port traffic on the 80%-busy binding pipe) but synchronized
//   with __syncthreads() instead of inline-asm {vmcnt(0); s_barrier}.
//   R10's correctness failure is attributed to the rule-#18 hazard class:
//   hipcc can reorder intrinsics across inline-asm waits it doesn't model.
//   __syncthreads() emits the SAME s_waitcnt vmcnt(0) lgkmcnt(0)+s_barrier
//   but with compiler-known barrier semantics (R2 ran this staging schedule
//   correctly; mapping is byte-identical to R8's reg-staged layout).
//   The vmcnt(0) drain sits a full ds_read+16-MFMA phase after issue ->
//   loads aged, drain cheap.
// ---------------------------------------------------------------------------
__launch_bounds__(256, 4)
__global__ void gemm_top2(const _Float16* __restrict__ xh, const _Float16* __restrict__ cth,
                          const float* __restrict__ csq, float* __restrict__ pv1,
                          int* __restrict__ pi1, float* __restrict__ pv2) {
  __shared__ __align__(16) unsigned char smem[32768];  // 2 bufs x (A 8K + B 8K)
  __shared__ float ep_v1[128][2], ep_v2[128][2];
  __shared__ int ep_i1[128][2];

  const int t = threadIdx.x;
  const int m0 = blockIdx.x * 128;
  const int n0 = blockIdx.y * 128;

  // staging: thread t owns rows m0+(t&127) / n0+(t&127), kq parity t>>7.
  const int srow = t & 127;
  const int kqp = t >> 7;  // 0/1 ; kq = kqp + 2*c2
  const half8* Ag = (const half8*)xh + (size_t)(m0 + srow);   // + kg*32768
  const half8* Bg = (const half8*)cth + (size_t)(n0 + srow);  // + kg*8192

  const int l = t & 63;
  const int w = t >> 6;
  const int wm = w >> 1, wn = w & 1;
  const int l15 = l & 15, lq = l >> 4;
  const int aBase = lq * 128 + wm * 64 + l15;        // + mf*16  (half8 idx)
  const int bBase = 512 + lq * 128 + wn * 64 + l15;  // + nf*16

  floatx4 acc[4][4] = {};
  const half8* S = (const half8*)smem;
  half8* SH = (half8*)smem;

  // stage tile kc into LDS buf via global_load_lds (wave-linear dest:
  // lane offset = l*16B within each 64-slot chunk).
  auto stage = [&](int buf, int kc) {
    const int bo = buf * 1024;
#pragma unroll
    for (int c2 = 0; c2 < 2; ++c2) {
      const size_t g = (size_t)(kc * 4 + kqp + 2 * c2);
      __builtin_amdgcn_global_load_lds(
          (const __attribute__((address_space(1))) void*)(Ag + g * 32768),
          (__attribute__((address_space(3))) void*)(SH + bo + c2 * 256 + t), 16, 0, 0);
      __builtin_amdgcn_global_load_lds(
          (const __attribute__((address_space(1))) void*)(Bg + g * 8192),
          (__attribute__((address_space(3))) void*)(SH + bo + 512 + c2 * 256 + t), 16, 0, 0);
    }
  };

  // prologue: stage tile 0 into buf0, drain + sync (compiler-visible).
  stage(0, 0);
  __syncthreads();

  for (int kc = 0; kc < 16; ++kc) {
    const int bo = (kc & 1) * 1024;
    if (kc < 15) stage((kc + 1) & 1, kc + 1);  // full compute phase to land
    half8 a[4], b[4];
#pragma unroll
    for (int f = 0; f < 4; ++f) {
      a[f] = S[bo + aBase + f * 16];
      b[f] = S[bo + bBase + f * 16];
    }
#pragma unroll
    for (int mf = 0; mf < 4; ++mf)
#pragma unroll
      for (int nf = 0; nf < 4; ++nf)
        acc[mf][nf] = __builtin_amdgcn_mfma_f32_16x16x32_f16(b[nf], a[mf], acc[mf][nf], 0, 0, 0);
    // drains vmcnt(0) (kc+1's loads, aged through ds_read+MFMA) + barrier;
    // compiler-known -> no intrinsic reordering across it.
    __syncthreads();
  }

  // ---- epilogue: top-2, lane-local over 16 centroids then 2 merge rounds.
  // acc[mf][nf][reg] = dot(xrow = m0+wm*64+mf*16+l15,
  //                        cent = n0+wn*64+nf*16+lq*4+reg)
  floatx4 cs4[4];
  const floatx4* csq4 = (const floatx4*)csq;
#pragma unroll
  for (int nf = 0; nf < 4; ++nf)
    cs4[nf] = csq4[(n0 >> 2) + wn * 16 + nf * 4 + lq];

  const int siBase = n0 + wn * 64 + lq * 4;

#pragma unroll
  for (int mf = 0; mf < 4; ++mf) {
    float v1 = INFINITY, v2 = INFINITY;
    int i1 = 0;
#pragma unroll
    for (int nf = 0; nf < 4; ++nf) {
#pragma unroll
      for (int reg = 0; reg < 4; ++reg) {
        float sv = fmaf(-2.f, acc[mf][nf][reg], cs4[nf][reg]);
        int si = siBase + nf * 16 + reg;
        if (sv < v1) { v2 = v1; v1 = sv; i1 = si; }
        else if (sv < v2) { v2 = sv; }
      }
    }
    // merge across the 4 lq-groups (lanes l15, l15+16, l15+32, l15+48)
#pragma unroll
    for (int off = 16; off <= 32; off <<= 1) {
      float w1 = __shfl_xor(v1, off, 64);
      int j1 = __shfl_xor(i1, off, 64);
      float w2 = __shfl_xor(v2, off, 64);
      if (w1 < v1 || (w1 == v1 && j1 < i1)) {
        v2 = fminf(v1, w2);
        v1 = w1; i1 = j1;
      } else {
        v2 = fminf(v2, w1);
      }
    }
    if (lq == 0) {
      int rl = wm * 64 + mf * 16 + l15;
      ep_v1[rl][wn] = v1;
      ep_i1[rl][wn] = i1;
      ep_v2[rl][wn] = v2;
    }
  }
  __syncthreads();
  if (t < 128) {
    float v1 = ep_v1[t][0], v2 = ep_v2[t][0];
    int i1 = ep_i1[t][0];
    float w1 = ep_v1[t][1], w2 = ep_v2[t][1];
    int j1 = ep_i1[t][1];
    if (w1 < v1 || (w1 == v1 && j1 < i1)) {
      v2 = fminf(v1, w2);
      v1 = w1; i1 = j1;
    } else {
      v2 = fminf(v2, w1);
    }
    const size_t o = (size_t)blockIdx.y * 32768 + m0 + t;
    pv1[o] = v1;
    pi1[o] = i1;
    pv2[o] = v2;
  }
}

// ---------------------------------------------------------------------------
// Kernel 2 (R7): merge 64 nblock top-2s — parallel over nb.  Associative
//   merge over total order (value, index) -> bit-identical to sequential.
// ---------------------------------------------------------------------------
__global__ void final_top2(const float* __restrict__ pv1, const int* __restrict__ pi1,
                           const float* __restrict__ pv2, int* __restrict__ out,
                           float* __restrict__ rowbest, unsigned int* __restrict__ cnt,
                           int* __restrict__ list) {
  __shared__ float sv1[8][33], sv2[8][33];
  __shared__ int si1[8][33];
  const int t = threadIdx.x;
  const int r = t & 31, c = t >> 5;  // c = nb-chunk 0..7
  const int row = blockIdx.x * 32 + r;
  float v1 = INFINITY, v2 = INFINITY;
  int i1 = 0;
#pragma unroll
  for (int k = 0; k < 8; ++k) {
    const size_t o = (size_t)(c * 8 + k) * 32768 + row;
    float w1 = pv1[o], w2 = pv2[o];
    int j1 = pi1[o];
    if (w1 < v1 || (w1 == v1 && j1 < i1)) {
      v2 = fminf(v1, w2);
      v1 = w1; i1 = j1;
    } else {
      v2 = fminf(v2, w1);
    }
  }
  sv1[c][r] = v1;
  sv2[c][r] = v2;
  si1[c][r] = i1;
  __syncthreads();
  if (c == 0) {
#pragma unroll
    for (int k = 1; k < 8; ++k) {
      float w1 = sv1[k][r], w2 = sv2[k][r];
      int j1 = si1[k][r];
      if (w1 < v1 || (w1 == v1 && j1 < i1)) {
        v2 = fminf(v1, w2);
        v1 = w1; i1 = j1;
      } else {
        v2 = fminf(v2, w1);
      }
    }
    out[row] = i1;
    rowbest[row] = v1;
    if (v2 - v1 < TAU) {
      unsigned int pos = atomicAdd(cnt, 1u);
      list[pos] = row;
    }
  }
}

// ---------------------------------------------------------------------------
// Kernel 3: candidate-set exact rescore for flagged rows.
// ---------------------------------------------------------------------------
__global__ void cand_refine(const float* __restrict__ x, const float* __restrict__ cen,
                            const float* __restrict__ csq, const float* __restrict__ pv1,
                            const int* __restrict__ pi1, const float* __restrict__ pv2,
                            const float* __restrict__ rowbest,
                            const unsigned int* __restrict__ cnt, const int* __restrict__ list,
                            unsigned int* __restrict__ cnt2, int* __restrict__ list2,
                            unsigned long long* __restrict__ slots, int* __restrict__ out) {
  __shared__ float xs[512];
  __shared__ int cand[CMAX];
  __shared__ int ccnt_s, needfull_s;
  __shared__ unsigned long long wbest[4];
  const int t = threadIdx.x;
  const int lane = t & 63, wid = t >> 6;
  const int n = (int)*cnt;
  for (int u = blockIdx.x; u < n; u += gridDim.x) {
    __syncthreads();  // protect previous iteration's xs/cand readers
    const int row = list[u];
    const int b = row >> 11, s = row & 2047;
    if (t == 0) { ccnt_s = 0; needfull_s = 0; }
    __syncthreads();
    xs[t] = x[((size_t)(b * 512 + t)) * 2048 + s];
    xs[t + 256] = x[((size_t)(b * 512 + t + 256)) * 2048 + s];
    const float thr = rowbest[row] + TAU;
    if (t < 64) {
      const size_t o = (size_t)t * 32768 + row;
      float w1 = pv1[o];
      if (w1 < thr) {
        int p = atomicAdd(&ccnt_s, 1);
        if (p < CMAX) cand[p] = pi1[o];
        if (pv2[o] < thr) needfull_s = 1;
      }
    }
    __syncthreads();
    int ccnt = ccnt_s < CMAX ? ccnt_s : CMAX;
    unsigned long long best = ~0ULL;
    for (int ci = wid; ci < ccnt; ci += 4) {
      const int k = cand[ci];
      float p0 = 0.f, p1 = 0.f;
#pragma unroll
      for (int j = 0; j < 4; ++j)
        p0 = fmaf(xs[lane + 64 * j], cen[(size_t)(lane + 64 * j) * 8192 + k], p0);
#pragma unroll
      for (int j = 4; j < 8; ++j)
        p1 = fmaf(xs[lane + 64 * j], cen[(size_t)(lane + 64 * j) * 8192 + k], p1);
      float d = p0 + p1;
#pragma unroll
      for (int off = 32; off >= 1; off >>= 1) d += __shfl_xor(d, off, 64);
      unsigned long long key = score_key(fmaf(-2.f, d, csq[k]), k);
      if (key < best) best = key;
    }
    if (lane == 0) wbest[wid] = best;
    __syncthreads();
    if (t == 0) {
      unsigned long long m = wbest[0];
#pragma unroll
      for (int w2 = 1; w2 < 4; ++w2)
        if (wbest[w2] < m) m = wbest[w2];
      out[row] = (int)(unsigned)(m & 0xFFFFFFFFULL);
      if (needfull_s) {
        slots[row] = ~0ULL;
        unsigned int pos = atomicAdd(cnt2, 1u);
        list2[pos] = row;
      }
    }
  }
}

// ---------------------------------------------------------------------------
// Kernel 4: full 8192-scan for the rare rows needing it.
// ---------------------------------------------------------------------------
__global__ void fullscan(const float* __restrict__ x, const float* __restrict__ cen,
                         const float* __restrict__ csq, const unsigned int* __restrict__ cnt2,
                         const int* __restrict__ list2, unsigned long long* __restrict__ slots) {
  __shared__ float xs[512];
  __shared__ unsigned long long red[256];
  const int t = threadIdx.x;
  const int n2 = (int)*cnt2;
  const int units = n2 * 16;
  for (int u = blockIdx.x; u < units; u += gridDim.x) {
    __syncthreads();
    const int row = list2[u >> 4];
    const int sl = u & 15;
    const int b = row >> 11, s = row & 2047;
    xs[t] = x[((size_t)(b * 512 + t)) * 2048 + s];
    xs[t + 256] = x[((size_t)(b * 512 + t + 256)) * 2048 + s];
    __syncthreads();
    const int k0 = sl * 512 + t;
    float tot0 = 0.f, tot1 = 0.f;
#pragma unroll
    for (int ch = 0; ch < 4; ++ch) {
      float a0 = 0.f, a1 = 0.f;
      for (int c = ch * 128; c < ch * 128 + 128; ++c) {
        float xv = xs[c];
        a0 = fmaf(xv, cen[(size_t)c * 8192 + k0], a0);
        a1 = fmaf(xv, cen[(size_t)c * 8192 + k0 + 256], a1);
      }
      tot0 += a0;
      tot1 += a1;
    }
    unsigned long long k1 = score_key(fmaf(-2.f, tot0, csq[k0]), k0);
    unsigned long long k2 = score_key(fmaf(-2.f, tot1, csq[k0 + 256]), k0 + 256);
    red[t] = k1 < k2 ? k1 : k2;
    __syncthreads();
    for (int off = 128; off >= 1; off >>= 1) {
      if (t < off && red[t + off] < red[t]) red[t] = red[t + off];
      __syncthreads();
    }
    if (t == 0) atomicMin(&slots[row], red[0]);
  }
}

// ---------------------------------------------------------------------------
// Kernel 5: fold fullscan results into labels.
// ---------------------------------------------------------------------------
__global__ void fixup2(const unsigned int* __restrict__ cnt2, const int* __restrict__ list2,
                       const unsigned long long* __restrict__ slots, int* __restrict__ out) {
  const int n2 = (int)*cnt2;
  for (int i = blockIdx.x * blockDim.x + threadIdx.x; i < n2; i += blockDim.x * gridDim.x) {
    const int row = list2[i];
    out[row] = (int)(unsigned)(slots[row] & 0xFFFFFFFFULL);
  }
}

// ---------------------------------------------------------------------------
// Fallback (only if ws too small): exact distances, slow but correct.
// ---------------------------------------------------------------------------
__global__ void fallback_kernel(const float* __restrict__ x, const float* __restrict__ cen,
                                int* __restrict__ out) {
  __shared__ float xrow[512];
  __shared__ float rv[256];
  __shared__ int ri[256];
  const int row = blockIdx.x;
  const int b = row >> 11, s = row & 2047;
  const int t = threadIdx.x;
  for (int c = t; c < 512; c += 256) xrow[c] = x[((size_t)b * 512 + c) * 2048 + s];
  __syncthreads();
  float bv = INFINITY;
  int bi = 0;
  for (int k = t; k < 8192; k += 256) {
    float d = 0.f;
    for (int c = 0; c < 512; ++c) {
      float diff = xrow[c] - cen[(size_t)c * 8192 + k];
      d = fmaf(diff, diff, d);
    }
    if (d < bv) { bv = d; bi = k; }
  }
  rv[t] = bv;
  ri[t] = bi;
  __syncthreads();
  for (int off = 128; off > 0; off >>= 1) {
    if (t < off) {
      if (rv[t + off] < rv[t] || (rv[t + off] == rv[t] && ri[t + off] < ri[t])) {
        rv[t] = rv[t + off];
        ri[t] = ri[t + off];
      }
    }
    __syncthreads();
  }
  if (t == 0) out[row] = ri[0];
}

// ---------------------------------------------------------------------------
extern "C" void kernel_launch(void* const* d_in, const int* in_sizes, int n_in,
                              void* d_out, int out_size, void* d_ws, size_t ws_size,
                              hipStream_t stream) {
  const float* x = (const float*)d_in[0];    // [16, 512, 2048]
  const float* cen = (const float*)d_in[1];  // [512, 8192]
  int* out = (int*)d_out;                    // [32768] int32 labels

  const size_t XSZ = (size_t)32768 * 512;  // halfs
  const size_t CSZ = (size_t)8192 * 512;   // halfs
  const size_t OFF_CTH = XSZ * 2;
  const size_t OFF_CSQ = OFF_CTH + CSZ * 2;
  const size_t OFF_PV1 = OFF_CSQ + 8192 * 4;
  const size_t OFF_PI1 = OFF_PV1 + (size_t)64 * 32768 * 4;
  const size_t OFF_PV2 = OFF_PI1 + (size_t)64 * 32768 * 4;
  const size_t OFF_RB = OFF_PV2 + (size_t)64 * 32768 * 4;
  const size_t OFF_SLOT = OFF_RB + (size_t)32768 * 4;
  const size_t OFF_LIST = OFF_SLOT + (size_t)32768 * 8;
  const size_t OFF_LIST2 = OFF_LIST + (size_t)32768 * 4;
  const size_t OFF_CNT = OFF_LIST2 + (size_t)32768 * 4;
  const size_t NEED = OFF_CNT + 16;

  if (ws_size < NEED) {
    fallback_kernel<<<32768, 256, 0, stream>>>(x, cen, out);
    return;
  }

  char* ws = (char*)d_ws;
  _Float16* xh = (_Float16*)ws;
  _Float16* cth = (_Float16*)(ws + OFF_CTH);
  float* csq = (float*)(ws + OFF_CSQ);
  float* pv1 = (float*)(ws + OFF_PV1);
  int* pi1 = (int*)(ws + OFF_PI1);
  float* pv2 = (float*)(ws + OFF_PV2);
  float* rowbest = (float*)(ws + OFF_RB);
  unsigned long long* slots = (unsigned long long*)(ws + OFF_SLOT);
  int* list = (int*)(ws + OFF_LIST);
  int* list2 = (int*)(ws + OFF_LIST2);
  unsigned int* cnts = (unsigned int*)(ws + OFF_CNT);  // [0]=cnt, [1]=cnt2

  tsplit_x<<<dim3(32, 16, 16), dim3(32, 8), 0, stream>>>(x, xh);
  tsplit_c<<<dim3(128, 16), dim3(32, 8), 0, stream>>>(cen, cth);
  csq_kernel<<<128, 256, 0, stream>>>(cen, csq, cnts);
  gemm_top2<<<dim3(256, 64), 256, 0, stream>>>(xh, cth, csq, pv1, pi1, pv2);
  final_top2<<<1024, 256, 0, stream>>>(pv1, pi1, pv2, out, rowbest, cnts, list);
  cand_refine<<<512, 256, 0, stream>>>(x, cen, csq, pv1, pi1, pv2, rowbest,
                                       cnts, list, cnts + 1, list2, slots, out);
  fullscan<<<256, 256, 0, stream>>>(x, cen, csq, cnts + 1, list2, slots);
  fixup2<<<4, 256, 0, stream>>>(cnts + 1, list2, slots, out);
}